// Round 13
// baseline (151.870 us; speedup 1.0000x reference)
//
#include <hip/hip_runtime.h>

// multi_triples_lstm v13: v10 skeleton (4-way unit-split, 256-thr WGs, 2048
// WGs, 1 exchange barrier/step) with TRANS-FREE-ISH activations:
//   tanh via clamped Pade(7,6): T(x) = x(135135+17325x^2+378x^4+x^6) /
//                                      (135135+62370x^2+3150x^4+28x^6)
//   sigmoid(a) = 0.5 + 0.5*T(a/2)  (0.5 folded into W rows of i,f,o)
//   shared denominators -> only 2 rcp-pairs per unit-pair (was 10 exp + 4 rcp)
// All activation math in packed f32x2 (v_pk_fma_f32 full-rate). This removes
// the quarter-rate trans burst that (per the constant-27us-idle ledger) acts
// as a convoy metronome across the 8 waves/SIMD.
//
// LDS (dynamic):
//   X   @ 0     : 16 rows x 1040B (fp16 feats; (b,t) at b*1040 + t*32)
//   HX0 @ 16640 : 1024B (64 lanes x 16B: dword d = wave d's packed h)
//   HX1 @ 17664 : 1024B (double buffer)
//   Z   @ 18688 : 32B zeros (x-frag quads 2,3)
//   fc2 scratch overlays X (16 rows x 144B)
#define LDS_BYTES 18720

typedef _Float16 f16x8 __attribute__((ext_vector_type(8)));
typedef __fp16   fp16x2 __attribute__((ext_vector_type(2)));
typedef float    f32x4 __attribute__((ext_vector_type(4)));
typedef float    f32x2 __attribute__((ext_vector_type(2)));

__global__ __launch_bounds__(256, 8)
void lstm_fused(const int* __restrict__ objs,
                const float* __restrict__ boxes,
                const int* __restrict__ preds,
                const int* __restrict__ subj,
                const float* __restrict__ obj_emb,
                const float* __restrict__ pred_emb,
                const float* __restrict__ W_ih,
                const float* __restrict__ W_hh,
                const float* __restrict__ b_ih,
                const float* __restrict__ b_hh,
                const float* __restrict__ fc2_W,
                const float* __restrict__ fc2_b,
                float* __restrict__ out)
{
    extern __shared__ char smem[];
    const int tid  = threadIdx.x;
    const int lane = tid & 63;
    const int wv   = tid >> 6;           // 0..3: which unit-pair quarter
    const int quad = lane >> 4;          // 0..3
    const int cidx = lane & 15;          // batch index
    const int XOFF = 0, HX0 = 16640, HX1 = 17664, ZOFF = 18688;

    if (tid < 8) ((int*)(smem + ZOFF))[tid] = 0;

    // ---- stage x features (fp16): 256 threads, 2 t each ----
    {
        int b  = tid >> 4;               // 0..15
        int t0 = (tid & 15) << 1;        // 0,2,...,30
        long gb = (long)blockIdx.x * 16 + b;
        int2 ov = *(const int2*)(objs  + gb * 32 + t0);
        int2 pv = *(const int2*)(preds + gb * 32 + t0);
        int2 sv = *(const int2*)(subj  + gb * 32 + t0);
        int oarr[2] = {ov.x, ov.y};
        int parr[2] = {pv.x, pv.y};
        int sarr[2] = {sv.x, sv.y};
        #pragma unroll
        for (int tt = 0; tt < 2; ++tt) {
            int t = t0 + tt;
            const float* eo = obj_emb  + oarr[tt] * 5;
            const float* ep = pred_emb + parr[tt] * 5;
            float4 bx = *(const float4*)(boxes + (gb * 32 + t) * 4);
            f16x8 lo, hi;
            lo[0]=(_Float16)eo[0]; lo[1]=(_Float16)eo[1]; lo[2]=(_Float16)eo[2];
            lo[3]=(_Float16)eo[3]; lo[4]=(_Float16)eo[4];
            lo[5]=(_Float16)ep[0]; lo[6]=(_Float16)ep[1]; lo[7]=(_Float16)ep[2];
            hi[0]=(_Float16)ep[3]; hi[1]=(_Float16)ep[4];
            hi[2]=(_Float16)(sarr[tt]==0 ? 1.0f : 0.0f);
            hi[3]=(_Float16)(sarr[tt]==1 ? 1.0f : 0.0f);
            hi[4]=(_Float16)bx.x; hi[5]=(_Float16)bx.y;
            hi[6]=(_Float16)bx.z; hi[7]=(_Float16)bx.w;
            char* dst = smem + XOFF + b * 1040 + t * 32;
            *(f16x8*)dst        = lo;
            *(f16x8*)(dst + 16) = hi;
        }
    }

    // ---- W fragments: wave wv, tile row m: unit u=8*(m>>2)+2*wv+(m&1),
    //      gate = tile*2 + ((m&3)>>1)  (0=i,1=f,2=g,3=o; canonical n=g*32+u)
    //      fold: sigmoid gates (i,f,o) * 0.5 (half-angle); g * 1.0
    f16x8 Wf[2][2];
    f32x4 bias4[2];
    #pragma unroll
    for (int tile = 0; tile < 2; ++tile) {
        int rm   = cidx & 3;
        int u    = 8 * (cidx >> 2) + 2 * wv + (rm & 1);
        int gate = tile * 2 + (rm >> 1);
        float scale = (gate == 2) ? 1.0f : 0.5f;
        int n = gate * 32 + u;
        #pragma unroll
        for (int ks = 0; ks < 2; ++ks) {
            f16x8 v;
            #pragma unroll
            for (int jj = 0; jj < 8; ++jj) {
                int k = ks * 32 + quad * 8 + jj;
                float val = (k < 16) ? W_ih[n * 16 + k]
                          : (k >= 32) ? W_hh[n * 32 + (k - 32)]
                          : 0.0f;
                v[jj] = (_Float16)(val * scale);
            }
            Wf[tile][ks] = v;
        }
        #pragma unroll
        for (int r = 0; r < 4; ++r) {
            int ur = 8 * quad + 2 * wv + (r & 1);
            int gr = tile * 2 + (r >> 1);
            float sc = (gr == 2) ? 1.0f : 0.5f;
            bias4[tile][r] = (b_ih[gr * 32 + ur] + b_hh[gr * 32 + ur]) * sc;
        }
    }

    // ---- addressing ----
    const bool qlow = (quad < 2);
    int       xaddr = qlow ? (XOFF + cidx * 1040 + quad * 16) : ZOFF;
    const int xinc  = qlow ? 32 : 0;
    const int slot16 = lane << 4;                    // 16B slot in HX buffer
    const int wr_off = slot16 + (wv << 2);           // own dword within slot

    __syncthreads();   // staging visible

    // prime: x[0] MFMAs (bias rides as C); h(0)=0
    f16x8 xfrag = *(const f16x8*)(smem + xaddr); xaddr += xinc;
    f32x4 accp[2];
    #pragma unroll
    for (int tile = 0; tile < 2; ++tile)
        accp[tile] = __builtin_amdgcn_mfma_f32_16x16x32_f16(Wf[tile][0], xfrag, bias4[tile], 0, 0, 0);

    union { int i[4]; f16x8 v; } hf;
    hf.i[0] = 0; hf.i[1] = 0; hf.i[2] = 0; hf.i[3] = 0;

    const f32x2 PC0 = {135135.0f, 135135.0f};
    const f32x2 PC1 = {17325.0f, 17325.0f};
    const f32x2 PC2 = {378.0f, 378.0f};
    const f32x2 PD1 = {62370.0f, 62370.0f};
    const f32x2 PD2 = {3150.0f, 3150.0f};
    const f32x2 PD3 = {28.0f, 28.0f};
    const f32x2 LIM = {5.0f, 5.0f};
    const f32x2 NLIM = {-5.0f, -5.0f};
    const f32x2 HALF = {0.5f, 0.5f};

    f32x2 cstv = {0.0f, 0.0f};
    f32x2 hv = {0.0f, 0.0f};

    // Pade(7,6) tanh: fills N(x), D(x); caller pre-clamps x to [-5,5]
    #define PADE(x, N, D) { f32x2 _x2 = (x)*(x); f32x2 _x4 = _x2*_x2;        \
        f32x2 _x6 = _x4*_x2;                                                  \
        N = _x2*PC1 + PC0; N = _x4*PC2 + N; N = N + _x6; N = N*(x);           \
        D = _x2*PD1 + PC0; D = _x4*PD2 + D; D = _x6*PD3 + D; }
    #define CLAMP2(x) __builtin_elementwise_min(__builtin_elementwise_max((x), NLIM), LIM)

    #pragma unroll 2
    for (int t = 0; t < 32; ++t) {
        // h-MFMAs: acc0 = {i(u0),i(u1),f(u0),f(u1)}, acc1 = {g(u0),g(u1),o(u0),o(u1)}
        f32x4 acc0 = __builtin_amdgcn_mfma_f32_16x16x32_f16(Wf[0][1], hf.v, accp[0], 0, 0, 0);
        f32x4 acc1 = __builtin_amdgcn_mfma_f32_16x16x32_f16(Wf[1][1], hf.v, accp[1], 0, 0, 0);

        // prefetch next x (t=31 reads row pad — discarded)
        f16x8 xn = *(const f16x8*)(smem + xaddr); xaddr += xinc;

        // rational activations (packed f32x2; only 4 scalar rcp per step)
        f32x2 xi = CLAMP2(((f32x2){acc0[0], acc0[1]}));
        f32x2 xf = CLAMP2(((f32x2){acc0[2], acc0[3]}));
        f32x2 xg = CLAMP2(((f32x2){acc1[0], acc1[1]}));
        f32x2 xo = CLAMP2(((f32x2){acc1[2], acc1[3]}));
        f32x2 Ni, Di, Nf, Df, Ng, Dg, No, Do;
        PADE(xi, Ni, Di);
        PADE(xf, Nf, Df);
        PADE(xg, Ng, Dg);
        PADE(xo, No, Do);

        // c = f*cp + i*g  with i=(Di+Ni)/(2Di) etc., g=Ng/Dg:
        //   c = [ (Df+Nf)*cp*Di*Dg + (Di+Ni)*Ng*Df ] / (2*Df*Di*Dg)
        f32x2 P    = Di * Dg;
        f32x2 R    = (Df + Nf) * cstv;  R = R * P;
        f32x2 S    = (Di + Ni) * Ng;    S = S * Df;
        f32x2 numC = (R + S) * HALF;
        f32x2 denC = Df * P;
        f32x2 rr   = {__builtin_amdgcn_rcpf(denC.x), __builtin_amdgcn_rcpf(denC.y)};
        f32x2 c    = numC * rr;
        cstv = c;
        f32x2 cc   = CLAMP2(c);
        f32x2 Nc, Dc;
        PADE(cc, Nc, Dc);

        // h = o * tanh(c) = (Do+No)*Nc / (2*Do*Dc)
        f32x2 U  = (Do + No) * Nc;
        f32x2 V  = Do * Dc;
        f32x2 r2 = {__builtin_amdgcn_rcpf(V.x), __builtin_amdgcn_rcpf(V.y)};
        hv = (U * r2) * HALF;

        union { fp16x2 h; int i; } pku;
        pku.h = __builtin_amdgcn_cvt_pkrtz(hv.x, hv.y);

        // publish own dword; barrier; gather hides under x-MFMAs
        char* buf = smem + ((t & 1) ? HX1 : HX0);
        *(int*)(buf + wr_off) = pku.i;
        __syncthreads();

        accp[0] = __builtin_amdgcn_mfma_f32_16x16x32_f16(Wf[0][0], xn, bias4[0], 0, 0, 0);
        accp[1] = __builtin_amdgcn_mfma_f32_16x16x32_f16(Wf[1][0], xn, bias4[1], 0, 0, 0);

        hf.v = *(const f16x8*)(buf + slot16);
    }

    // ---- epilogue: fc2 on final h (fp32 via LDS scratch over X) ----
    __syncthreads();
    {
        int u0 = 8 * quad + 2 * wv;
        *(float2*)(smem + cidx * 144 + u0 * 4) = (float2){hv.x, hv.y};
    }
    __syncthreads();

    if (tid < 64) {
        int b = tid >> 2, jj = tid & 3;
        const float* fw   = fc2_W + jj * 32;
        const float* hrow = (const float*)(smem + b * 144);
        float s = fc2_b[jj];
        #pragma unroll
        for (int k = 0; k < 8; ++k) {
            float4 hvv = *(const float4*)(hrow + k * 4);
            s += fw[k*4+0] * hvv.x + fw[k*4+1] * hvv.y
               + fw[k*4+2] * hvv.z + fw[k*4+3] * hvv.w;
        }
        s = fminf(fmaxf(s, 0.0f), 1.0f);
        out[(long)blockIdx.x * 64 + tid] = s;
    }
}

extern "C" void kernel_launch(void* const* d_in, const int* in_sizes, int n_in,
                              void* d_out, int out_size, void* d_ws, size_t ws_size,
                              hipStream_t stream)
{
    // inputs: 0 objs(i32) 1 boxes(f32) 2 preds(i32) 3 subj(i32) 4 target(unused)
    //         5 obj_emb 6 pred_emb 7 W_ih 8 W_hh 9 b_ih 10 b_hh 11 fc2_W 12 fc2_b
    lstm_fused<<<2048, 256, LDS_BYTES, stream>>>(
        (const int*)d_in[0], (const float*)d_in[1], (const int*)d_in[2],
        (const int*)d_in[3],
        (const float*)d_in[5], (const float*)d_in[6],
        (const float*)d_in[7], (const float*)d_in[8],
        (const float*)d_in[9], (const float*)d_in[10],
        (const float*)d_in[11], (const float*)d_in[12],
        (float*)d_out);
}

// Round 14
// 129.119 us; speedup vs baseline: 1.1762x; 1.1762x over previous
//
#include <hip/hip_runtime.h>

// multi_triples_lstm v14 (= v11 best-known + ds_read hoist):
// 4-way unit-split, 256-thr WGs, 2048 WGs, 1 exchange barrier/step.
//  - shared-denominator exp algebra (7 trans/unit-step), packed f32x2
//  - cvt_pkrtz h-pack; scales folded into fp16 weights
//  - HX layout: lane L's 4 partner dwords contiguous at L*16 -> 1 ds_write_b32
//    + 1 ds_read_b128; the read is issued IMMEDIATELY after the barrier so its
//    latency hides under the 2 x-MFMAs + next x-prefetch (v11 had it last).
//  - t-loop fully unrolled.
//
// LDS (dynamic):
//   X   @ 0     : 16 rows x 1040B (fp16 feats; (b,t) at b*1040 + t*32)
//   HX0 @ 16640 : 1024B (64 lanes x 16B: dword d = wave d's packed h)
//   HX1 @ 17664 : 1024B (double buffer)
//   Z   @ 18688 : 32B zeros (x-frag quads 2,3)
//   fc2 scratch overlays X (16 rows x 144B)
#define LDS_BYTES 18720

typedef _Float16 f16x8 __attribute__((ext_vector_type(8)));
typedef __fp16   fp16x2 __attribute__((ext_vector_type(2)));
typedef float    f32x4 __attribute__((ext_vector_type(4)));
typedef float    f32x2 __attribute__((ext_vector_type(2)));

#define LOG2E     1.44269504088896f
#define TWO_LOG2E 2.88539008177793f

__global__ __launch_bounds__(256, 8)
void lstm_fused(const int* __restrict__ objs,
                const float* __restrict__ boxes,
                const int* __restrict__ preds,
                const int* __restrict__ subj,
                const float* __restrict__ obj_emb,
                const float* __restrict__ pred_emb,
                const float* __restrict__ W_ih,
                const float* __restrict__ W_hh,
                const float* __restrict__ b_ih,
                const float* __restrict__ b_hh,
                const float* __restrict__ fc2_W,
                const float* __restrict__ fc2_b,
                float* __restrict__ out)
{
    extern __shared__ char smem[];
    const int tid  = threadIdx.x;
    const int lane = tid & 63;
    const int wv   = tid >> 6;           // 0..3: which unit-pair quarter
    const int quad = lane >> 4;          // 0..3
    const int cidx = lane & 15;          // batch index
    const int XOFF = 0, HX0 = 16640, HX1 = 17664, ZOFF = 18688;

    if (tid < 8) ((int*)(smem + ZOFF))[tid] = 0;

    // ---- stage x features (fp16): 256 threads, 2 t each ----
    {
        int b  = tid >> 4;               // 0..15
        int t0 = (tid & 15) << 1;        // 0,2,...,30
        long gb = (long)blockIdx.x * 16 + b;
        int2 ov = *(const int2*)(objs  + gb * 32 + t0);
        int2 pv = *(const int2*)(preds + gb * 32 + t0);
        int2 sv = *(const int2*)(subj  + gb * 32 + t0);
        int oarr[2] = {ov.x, ov.y};
        int parr[2] = {pv.x, pv.y};
        int sarr[2] = {sv.x, sv.y};
        #pragma unroll
        for (int tt = 0; tt < 2; ++tt) {
            int t = t0 + tt;
            const float* eo = obj_emb  + oarr[tt] * 5;
            const float* ep = pred_emb + parr[tt] * 5;
            float4 bx = *(const float4*)(boxes + (gb * 32 + t) * 4);
            f16x8 lo, hi;
            lo[0]=(_Float16)eo[0]; lo[1]=(_Float16)eo[1]; lo[2]=(_Float16)eo[2];
            lo[3]=(_Float16)eo[3]; lo[4]=(_Float16)eo[4];
            lo[5]=(_Float16)ep[0]; lo[6]=(_Float16)ep[1]; lo[7]=(_Float16)ep[2];
            hi[0]=(_Float16)ep[3]; hi[1]=(_Float16)ep[4];
            hi[2]=(_Float16)(sarr[tt]==0 ? 1.0f : 0.0f);
            hi[3]=(_Float16)(sarr[tt]==1 ? 1.0f : 0.0f);
            hi[4]=(_Float16)bx.x; hi[5]=(_Float16)bx.y;
            hi[6]=(_Float16)bx.z; hi[7]=(_Float16)bx.w;
            char* dst = smem + XOFF + b * 1040 + t * 32;
            *(f16x8*)dst        = lo;
            *(f16x8*)(dst + 16) = hi;
        }
    }

    // ---- W fragments: wave wv, tile row m: unit u=8*(m>>2)+2*wv+(m&1),
    //      gate = tile*2 + ((m&3)>>1)  (0=i,1=f,2=g,3=o; canonical n=g*32+u)
    f16x8 Wf[2][2];
    f32x4 bias4[2];
    #pragma unroll
    for (int tile = 0; tile < 2; ++tile) {
        int rm   = cidx & 3;
        int u    = 8 * (cidx >> 2) + 2 * wv + (rm & 1);
        int gate = tile * 2 + (rm >> 1);
        float scale = (gate == 2) ? TWO_LOG2E : -LOG2E;
        int n = gate * 32 + u;
        #pragma unroll
        for (int ks = 0; ks < 2; ++ks) {
            f16x8 v;
            #pragma unroll
            for (int jj = 0; jj < 8; ++jj) {
                int k = ks * 32 + quad * 8 + jj;
                float val = (k < 16) ? W_ih[n * 16 + k]
                          : (k >= 32) ? W_hh[n * 32 + (k - 32)]
                          : 0.0f;
                v[jj] = (_Float16)(val * scale);
            }
            Wf[tile][ks] = v;
        }
        #pragma unroll
        for (int r = 0; r < 4; ++r) {
            int ur = 8 * quad + 2 * wv + (r & 1);
            int gr = tile * 2 + (r >> 1);
            float sc = (gr == 2) ? TWO_LOG2E : -LOG2E;
            bias4[tile][r] = (b_ih[gr * 32 + ur] + b_hh[gr * 32 + ur]) * sc;
        }
    }

    // ---- addressing ----
    const bool qlow = (quad < 2);
    int       xaddr = qlow ? (XOFF + cidx * 1040 + quad * 16) : ZOFF;
    const int xinc  = qlow ? 32 : 0;
    const int slot16 = lane << 4;                    // 16B slot in HX buffer
    const int wr_off = slot16 + (wv << 2);           // own dword within slot

    __syncthreads();   // staging visible

    // prime: x[0] MFMAs (bias rides as C); h(0)=0
    f16x8 xfrag = *(const f16x8*)(smem + xaddr); xaddr += xinc;
    f32x4 accp[2];
    #pragma unroll
    for (int tile = 0; tile < 2; ++tile)
        accp[tile] = __builtin_amdgcn_mfma_f32_16x16x32_f16(Wf[tile][0], xfrag, bias4[tile], 0, 0, 0);

    union { int i[4]; f16x8 v; } hf;
    hf.i[0] = 0; hf.i[1] = 0; hf.i[2] = 0; hf.i[3] = 0;
    const f32x2 one = {1.0f, 1.0f};
    f32x2 cstv = {0.0f, 0.0f};
    f32x2 hv = {0.0f, 0.0f};

    #pragma unroll
    for (int t = 0; t < 32; ++t) {
        // h-MFMAs: acc0 = {i(u0),i(u1),f(u0),f(u1)}, acc1 = {g(u0),g(u1),o(u0),o(u1)}
        f32x4 acc0 = __builtin_amdgcn_mfma_f32_16x16x32_f16(Wf[0][1], hf.v, accp[0], 0, 0, 0);
        f32x4 acc1 = __builtin_amdgcn_mfma_f32_16x16x32_f16(Wf[1][1], hf.v, accp[1], 0, 0, 0);

        // prefetch next x (t=31 reads row pad — discarded)
        f16x8 xn = *(const f16x8*)(smem + xaddr); xaddr += xinc;

        // shared-denominator activations, packed f32x2 (v_pk_* full-rate ops)
        f32x2 Ei = {__builtin_amdgcn_exp2f(acc0[0]), __builtin_amdgcn_exp2f(acc0[1])};
        f32x2 Ef = {__builtin_amdgcn_exp2f(acc0[2]), __builtin_amdgcn_exp2f(acc0[3])};
        f32x2 Eg = {__builtin_amdgcn_exp2f(acc1[0]), __builtin_amdgcn_exp2f(acc1[1])};
        f32x2 Eo = {__builtin_amdgcn_exp2f(acc1[2]), __builtin_amdgcn_exp2f(acc1[3])};

        f32x2 t1  = Ei + one;
        f32x2 dig = t1 * Eg + t1;                    // (1+Ei)(1+Eg)
        f32x2 tf  = Ef + one;
        f32x2 nn  = (Eg - one) * tf + cstv * dig;
        f32x2 den = tf * dig;
        f32x2 rde = {__builtin_amdgcn_rcpf(den.x), __builtin_amdgcn_rcpf(den.y)};
        f32x2 c   = nn * rde;
        cstv = c;
        f32x2 cl  = c * TWO_LOG2E;
        f32x2 Ec  = {__builtin_amdgcn_exp2f(cl.x), __builtin_amdgcn_exp2f(cl.y)};
        f32x2 to  = Eo + one;
        f32x2 dh  = to * Ec + to;                    // (1+Eo)(1+Ec)
        f32x2 rdh = {__builtin_amdgcn_rcpf(dh.x), __builtin_amdgcn_rcpf(dh.y)};
        hv = (Ec - one) * rdh;

        union { fp16x2 h; int i; } pku;
        pku.h = __builtin_amdgcn_cvt_pkrtz(hv.x, hv.y);

        // publish own dword; barrier; gather FIRST (latency overlaps x-MFMAs)
        char* buf = smem + ((t & 1) ? HX1 : HX0);
        *(int*)(buf + wr_off) = pku.i;
        __syncthreads();

        hf.v = *(const f16x8*)(buf + slot16);

        // x-MFMAs for next step — issue inside the ds_read latency window
        accp[0] = __builtin_amdgcn_mfma_f32_16x16x32_f16(Wf[0][0], xn, bias4[0], 0, 0, 0);
        accp[1] = __builtin_amdgcn_mfma_f32_16x16x32_f16(Wf[1][0], xn, bias4[1], 0, 0, 0);
    }

    // ---- epilogue: fc2 on final h (fp32 via LDS scratch over X) ----
    __syncthreads();
    {
        int u0 = 8 * quad + 2 * wv;
        *(float2*)(smem + cidx * 144 + u0 * 4) = (float2){hv.x, hv.y};
    }
    __syncthreads();

    if (tid < 64) {
        int b = tid >> 2, jj = tid & 3;
        const float* fw   = fc2_W + jj * 32;
        const float* hrow = (const float*)(smem + b * 144);
        float s = fc2_b[jj];
        #pragma unroll
        for (int k = 0; k < 8; ++k) {
            float4 hvv = *(const float4*)(hrow + k * 4);
            s += fw[k*4+0] * hvv.x + fw[k*4+1] * hvv.y
               + fw[k*4+2] * hvv.z + fw[k*4+3] * hvv.w;
        }
        s = fminf(fmaxf(s, 0.0f), 1.0f);
        out[(long)blockIdx.x * 64 + tid] = s;
    }
}

extern "C" void kernel_launch(void* const* d_in, const int* in_sizes, int n_in,
                              void* d_out, int out_size, void* d_ws, size_t ws_size,
                              hipStream_t stream)
{
    // inputs: 0 objs(i32) 1 boxes(f32) 2 preds(i32) 3 subj(i32) 4 target(unused)
    //         5 obj_emb 6 pred_emb 7 W_ih 8 W_hh 9 b_ih 10 b_hh 11 fc2_W 12 fc2_b
    lstm_fused<<<2048, 256, LDS_BYTES, stream>>>(
        (const int*)d_in[0], (const float*)d_in[1], (const int*)d_in[2],
        (const int*)d_in[3],
        (const float*)d_in[5], (const float*)d_in[6],
        (const float*)d_in[7], (const float*)d_in[8],
        (const float*)d_in[9], (const float*)d_in[10],
        (const float*)d_in[11], (const float*)d_in[12],
        (float*)d_out);
}